// Round 16
// baseline (159.213 us; speedup 1.0000x reference)
//
#include <hip/hip_runtime.h>
#include <hip/hip_bf16.h>

#define NN 10000
#define NE 320000
#define PANEL 32
#define MLP_BLOCKS 313   // ceil(10000/32)

typedef __attribute__((ext_vector_type(8))) short bf16x8;     // MFMA A/B frag (4 VGPRs)
typedef __attribute__((ext_vector_type(4))) float f32x4;      // MFMA C/D frag
typedef __attribute__((ext_vector_type(8))) unsigned short ushort8;

// split fp32 -> bf16 hi + bf16 lo (a ~= hi + lo, residual ~2^-16 relative)
__device__ __forceinline__ void split_bf16(float a, unsigned short& hi, unsigned short& lo) {
  union { float f; unsigned int u; } v; v.f = a;
  hi = (unsigned short)(v.u >> 16);
  union { float f; unsigned int u; } h; h.u = (unsigned int)hi << 16;
  float r = a - h.f;                      // exact
  union { float f; unsigned int u; } w; w.f = r;
  lo = (unsigned short)(w.u >> 16);
}

// ---------------- prep: weight transpose+split to [N][K] hi/lo, deg=0 --------
// grid 384 x 256 = 98304 threads exactly
__global__ __launch_bounds__(256) void prep_kernel(
    const float* __restrict__ W1, unsigned short* __restrict__ W1thi, unsigned short* __restrict__ W1tlo,
    const float* __restrict__ W2, unsigned short* __restrict__ W2thi, unsigned short* __restrict__ W2tlo,
    const float* __restrict__ Wo, unsigned short* __restrict__ Wothi, unsigned short* __restrict__ Wotlo,
    int* __restrict__ deg) {
  int i = blockIdx.x * 256 + threadIdx.x;
  if (i < 2500) ((int4*)deg)[i] = make_int4(0, 0, 0, 0);       // 10000 ints
  if (i < 32768) {                       // W1 [128][256] -> W1t [256][128]
    int n = i >> 7, k = i & 127;
    unsigned short h, l; split_bf16(W1[k * 256 + n], h, l);
    W1thi[i] = h; W1tlo[i] = l;
  }
  if (i < 65536) {                       // W2 [256][256] -> W2t [256][256]
    int n = i >> 8, k = i & 255;
    unsigned short h, l; split_bf16(W2[k * 256 + n], h, l);
    W2thi[i] = h; W2tlo[i] = l;
  }
  if (i >= 65536) {                      // Wo [256][128] -> Wot [128][256]
    int o = i - 65536;
    int n = o >> 8, k = o & 255;
    unsigned short h, l; split_bf16(Wo[k * 128 + n], h, l);
    Wothi[o] = h; Wotlo[o] = l;
  }
}

// ---- one MFMA layer: A from LDS (32x[K] hi/lo, XOR-swizzled), B direct from
// global [N][K] hi/lo (L2-resident). acc = A@B with 3-MFMA split product. ----
template<int K, int NFRAG>
__device__ __forceinline__ void layer_mfma(
    const unsigned short* Ah, const unsigned short* Al,
    const unsigned short* __restrict__ Bthi, const unsigned short* __restrict__ Btlo,
    int lane, int colbase, f32x4 (&acc)[2][NFRAG]) {
  const int l15 = lane & 15, l16 = lane >> 4;
#pragma unroll
  for (int m = 0; m < 2; m++)
#pragma unroll
    for (int n = 0; n < NFRAG; n++) acc[m][n] = (f32x4){0.f, 0.f, 0.f, 0.f};
#pragma unroll 2
  for (int kk = 0; kk < K / 32; ++kk) {
    bf16x8 aH[2], aL[2], bH[NFRAG], bL[NFRAG];
#pragma unroll
    for (int m = 0; m < 2; m++) {
      int r = m * 16 + l15;
      int c = (kk * 4 + l16) ^ (r & 7);            // same involution as writer
      aH[m] = *(const bf16x8*)&Ah[r * 256 + c * 8];
      aL[m] = *(const bf16x8*)&Al[r * 256 + c * 8];
    }
#pragma unroll
    for (int n = 0; n < NFRAG; n++) {
      int col = colbase + n * 16 + l15;
      size_t off = (size_t)col * K + kk * 32 + l16 * 8;
      bH[n] = *(const bf16x8*)&Bthi[off];
      bL[n] = *(const bf16x8*)&Btlo[off];
    }
#pragma unroll
    for (int m = 0; m < 2; m++)
#pragma unroll
      for (int n = 0; n < NFRAG; n++) {
        acc[m][n] = __builtin_amdgcn_mfma_f32_16x16x32_bf16(aH[m], bH[n], acc[m][n], 0, 0, 0);
        acc[m][n] = __builtin_amdgcn_mfma_f32_16x16x32_bf16(aH[m], bL[n], acc[m][n], 0, 0, 0);
        acc[m][n] = __builtin_amdgcn_mfma_f32_16x16x32_bf16(aL[m], bH[n], acc[m][n], 0, 0, 0);
      }
  }
}

// ---- activate + split + write back into Abuf (becomes next layer's A) ----
// ACT: 1 = tanh, 2 = sigmoid(tanh)
template<int ACT>
__device__ __forceinline__ void writeback_lds(
    unsigned short* Ah, unsigned short* Al, f32x4 (&acc)[2][2],
    const float* __restrict__ bias, int lane, int colbase) {
  const int l15 = lane & 15, l16 = lane >> 4;
#pragma unroll
  for (int n = 0; n < 2; n++) {
    int col = colbase + n * 16 + l15;
    float bv = bias[col];
#pragma unroll
    for (int m = 0; m < 2; m++)
#pragma unroll
      for (int j = 0; j < 4; j++) {
        int r = m * 16 + l16 * 4 + j;              // C/D layout: row=(lane>>4)*4+j
        float v = acc[m][n][j] + bv;
        if (ACT == 1) v = tanhf(v);
        else v = 1.f / (1.f + expf(-tanhf(v)));
        unsigned short h, l; split_bf16(v, h, l);
        int c = col >> 3, e = col & 7;             // element k=col -> chunk,elem
        int idx = r * 256 + ((c ^ (r & 7)) * 8) + e;
        Ah[idx] = h; Al[idx] = l;
      }
  }
}

// ---------------- megakernel: 3-layer MLP fused (+ count as extra blocks) ----
// blocks [0,313): one 32-row panel each, 8 waves (each wave owns 32 cols of
// layers 1/2 and 16 cols of layer 3); A resident in LDS (32KB) across layers.
// blocks [313,1563): edge-degree count (deg zeroed by prep, a prior dispatch)
__global__ __launch_bounds__(512) void mega_kernel(
    const float* __restrict__ X,
    const unsigned short* __restrict__ W1thi, const unsigned short* __restrict__ W1tlo,
    const float* __restrict__ b1,
    const unsigned short* __restrict__ W2thi, const unsigned short* __restrict__ W2tlo,
    const float* __restrict__ b2,
    const unsigned short* __restrict__ Wothi, const unsigned short* __restrict__ Wotlo,
    float* __restrict__ hproj,
    const int* __restrict__ edst, int* __restrict__ deg) {
  if (blockIdx.x >= MLP_BLOCKS) {
    int e = (blockIdx.x - MLP_BLOCKS) * 512 + threadIdx.x;
    if (e < NE) atomicAdd(&deg[edst[e]], 1);
    return;
  }
  __shared__ unsigned short Ah[PANEL * 256], Al[PANEL * 256];   // 16KB + 16KB
  const int tid = threadIdx.x, lane = tid & 63, w = tid >> 6;
  const int row0 = blockIdx.x * PANEL;

  // stage X fp32 [32][128] -> split hi/lo; exactly 1 chunk-slot per thread
  {
    int r = tid >> 4, c = tid & 15;               // 32 rows x 16 chunks = 512
    int gr = row0 + r; if (gr > NN - 1) gr = NN - 1;
    const float* xp = &X[(size_t)gr * 128 + c * 8];
    float4 x0 = *(const float4*)xp;
    float4 x1 = *(const float4*)(xp + 4);
    unsigned short h0, l0, h1, l1, h2, l2, h3, l3;
    unsigned short h4, l4, h5, l5, h6, l6, h7, l7;
    split_bf16(x0.x, h0, l0); split_bf16(x0.y, h1, l1);
    split_bf16(x0.z, h2, l2); split_bf16(x0.w, h3, l3);
    split_bf16(x1.x, h4, l4); split_bf16(x1.y, h5, l5);
    split_bf16(x1.z, h6, l6); split_bf16(x1.w, h7, l7);
    ushort8 h, l;
    h[0] = h0; h[1] = h1; h[2] = h2; h[3] = h3;
    h[4] = h4; h[5] = h5; h[6] = h6; h[7] = h7;
    l[0] = l0; l[1] = l1; l[2] = l2; l[3] = l3;
    l[4] = l4; l[5] = l5; l[6] = l6; l[7] = l7;
    int base = r * 256 + ((c ^ (r & 7)) * 8);
    *(ushort8*)&Ah[base] = h;
    *(ushort8*)&Al[base] = l;
  }
  __syncthreads();

  { // layer 1: K=128 -> N=256, tanh (wave w owns cols [w*32, w*32+32))
    f32x4 acc[2][2];
    layer_mfma<128, 2>(Ah, Al, W1thi, W1tlo, lane, w * 32, acc);
    __syncthreads();                               // all reads of A done
    writeback_lds<1>(Ah, Al, acc, b1, lane, w * 32);
    __syncthreads();
  }
  { // layer 2: K=256 -> N=256, sigmoid(tanh)
    f32x4 acc[2][2];
    layer_mfma<256, 2>(Ah, Al, W2thi, W2tlo, lane, w * 32, acc);
    __syncthreads();
    writeback_lds<2>(Ah, Al, acc, b2, lane, w * 32);
    __syncthreads();
  }
  { // layer 3: K=256 -> N=128 (wave owns 16 cols), no bias -> global hproj
    f32x4 acc[2][1];
    layer_mfma<256, 1>(Ah, Al, Wothi, Wotlo, lane, w * 16, acc);
    const int l15 = lane & 15, l16 = lane >> 4;
    int col = w * 16 + l15;
#pragma unroll
    for (int m = 0; m < 2; m++)
#pragma unroll
      for (int j = 0; j < 4; j++) {
        int grow = row0 + m * 16 + l16 * 4 + j;
        if (grow < NN) hproj[(size_t)grow * 128 + col] = acc[m][0][j];
      }
  }
}

// 1-block exclusive scan: 1024 thr x 10 nodes, shfl wave-scan, 3 barriers
__global__ __launch_bounds__(1024) void scan_kernel(
    const int* __restrict__ deg, int* __restrict__ offs, int* __restrict__ cursor) {
  __shared__ int wsum[16];
  int t = threadIdx.x;
  int base = t * 10;
  int loc[10];
  int s = 0;
  if (base < NN) {
#pragma unroll
    for (int i = 0; i < 10; i++) {
      int idx = base + i;
      int v = (idx < NN) ? deg[idx] : 0;
      loc[i] = s; s += v;
    }
  }
  int lane = t & 63, w = t >> 6;
  int incl = s;
  for (int off = 1; off < 64; off <<= 1) {
    int u = __shfl_up(incl, off, 64);
    if (lane >= off) incl += u;
  }
  if (lane == 63) wsum[w] = incl;
  __syncthreads();
  if (t == 0) {
    int c = 0;
#pragma unroll
    for (int i = 0; i < 16; i++) { int v = wsum[i]; wsum[i] = c; c += v; }
  }
  __syncthreads();
  int ex = wsum[w] + incl - s;
  if (base < NN) {
#pragma unroll
    for (int i = 0; i < 10; i++) {
      int idx = base + i;
      if (idx < NN) { int o = ex + loc[i]; offs[idx] = o; cursor[idx] = o; }
    }
  }
}

__global__ void fill_kernel(const int* __restrict__ src, const int* __restrict__ dst,
                            int* __restrict__ cursor, int* __restrict__ csr, int n) {
  int i = blockIdx.x * blockDim.x + threadIdx.x;
  if (i < n) {
    int d = dst[i];
    int pos = atomicAdd(&cursor[d], 1);
    csr[pos] = src[i];
  }
}

// ---------------- segment mean over PROJECTED rows (128 cols) + bias -> out
__global__ __launch_bounds__(256) void aggregate_kernel(
    const float* __restrict__ hproj, const int* __restrict__ csr,
    const int* __restrict__ offs, const int* __restrict__ deg,
    const float* __restrict__ bo, float* __restrict__ out, int n_nodes) {
  int wave = threadIdx.x >> 6;
  int lane = threadIdx.x & 63;
  int node = blockIdx.x * 4 + wave;
  if (node >= n_nodes) return;
  int start = offs[node];
  int d = deg[node];
  const float2* h2 = (const float2*)hproj;
  float2 acc0 = make_float2(0.f, 0.f), acc1 = make_float2(0.f, 0.f);
  for (int t0 = 0; t0 < d; t0 += 64) {
    int rem = d - t0; if (rem > 64) rem = 64;
    int idx = (lane < rem) ? csr[start + t0 + lane] : 0;
    int j = 0;
    for (; j + 8 <= rem; j += 8) {
      int s0 = __shfl(idx, j + 0), s1 = __shfl(idx, j + 1);
      int s2 = __shfl(idx, j + 2), s3 = __shfl(idx, j + 3);
      int s4 = __shfl(idx, j + 4), s5 = __shfl(idx, j + 5);
      int s6 = __shfl(idx, j + 6), s7 = __shfl(idx, j + 7);
      float2 v0 = h2[s0 * 64 + lane], v1 = h2[s1 * 64 + lane];
      float2 v2 = h2[s2 * 64 + lane], v3 = h2[s3 * 64 + lane];
      float2 v4 = h2[s4 * 64 + lane], v5 = h2[s5 * 64 + lane];
      float2 v6 = h2[s6 * 64 + lane], v7 = h2[s7 * 64 + lane];
      acc0.x += (v0.x + v1.x) + (v2.x + v3.x);
      acc0.y += (v0.y + v1.y) + (v2.y + v3.y);
      acc1.x += (v4.x + v5.x) + (v6.x + v7.x);
      acc1.y += (v4.y + v5.y) + (v6.y + v7.y);
    }
    for (; j < rem; j++) {
      int s = __shfl(idx, j);
      float2 v = h2[s * 64 + lane];
      acc0.x += v.x; acc0.y += v.y;
    }
  }
  float scale = 1.f / fmaxf((float)d, 1.f);
  float2 b = ((const float2*)bo)[lane];
  float2 o;
  o.x = fmaf(acc0.x + acc1.x, scale, b.x);
  o.y = fmaf(acc0.y + acc1.y, scale, b.y);
  ((float2*)out)[node * 64 + lane] = o;
}

extern "C" void kernel_launch(void* const* d_in, const int* in_sizes, int n_in,
                              void* d_out, int out_size, void* d_ws, size_t ws_size,
                              hipStream_t stream) {
  const float* X    = (const float*)d_in[0];   // [10000,128]
  const int*   esrc = (const int*)d_in[1];     // [320000]
  const int*   edst = (const int*)d_in[2];     // [320000]
  const float* W1   = (const float*)d_in[3];   // [128,256]
  const float* b1   = (const float*)d_in[4];
  const float* W2   = (const float*)d_in[5];   // [256,256]
  const float* b2   = (const float*)d_in[6];
  const float* Wo   = (const float*)d_in[7];   // [256,128]
  const float* bo   = (const float*)d_in[8];
  float* out = (float*)d_out;                  // [10000,128]

  // workspace: hproj (5.12MB) + weight hi/lo (512KB) + CSR ints (~1.4MB)
  char* p = (char*)d_ws;
  size_t needed = (size_t)NN * 128 * 4
                + (size_t)(32768 + 65536 + 32768) * 2 * 2
                + (size_t)(3 * NN + NE) * 4;
  if (ws_size < needed) return;

  float* hproj = (float*)p;                   p += (size_t)NN * 128 * 4;
  unsigned short* W1thi = (unsigned short*)p; p += 32768 * 2;
  unsigned short* W1tlo = (unsigned short*)p; p += 32768 * 2;
  unsigned short* W2thi = (unsigned short*)p; p += 65536 * 2;
  unsigned short* W2tlo = (unsigned short*)p; p += 65536 * 2;
  unsigned short* Wothi = (unsigned short*)p; p += 32768 * 2;
  unsigned short* Wotlo = (unsigned short*)p; p += 32768 * 2;
  int* deg    = (int*)p; p += (size_t)NN * 4;
  int* offs   = (int*)p; p += (size_t)NN * 4;
  int* cursor = (int*)p; p += (size_t)NN * 4;
  int* csr    = (int*)p; p += (size_t)NE * 4;

  // 1) weights transpose+split, deg=0
  prep_kernel<<<384, 256, 0, stream>>>(W1, W1thi, W1tlo, W2, W2thi, W2tlo,
                                       Wo, Wothi, Wotlo, deg);
  // 2) fused 3-layer MLP + projection (blocks 0..312) and degree count (rest)
  mega_kernel<<<MLP_BLOCKS + (NE + 511) / 512, 512, 0, stream>>>(
      X, W1thi, W1tlo, b1, W2thi, W2tlo, b2, Wothi, Wotlo, hproj, edst, deg);
  // 3) offsets
  scan_kernel<<<1, 1024, 0, stream>>>(deg, offs, cursor);
  // 4) CSR fill
  fill_kernel<<<(NE + 255) / 256, 256, 0, stream>>>(esrc, edst, cursor, csr, NE);
  // 5) neighbor mean + fused bo -> d_out
  aggregate_kernel<<<(NN + 3) / 4, 256, 0, stream>>>(hproj, csr, offs, deg, bo, out, NN);
}